// Round 1
// baseline (7743.936 us; speedup 1.0000x reference)
//
#include <hip/hip_runtime.h>
#include <math.h>

#define S_LEN 8192
#define L_CH 12

typedef _Float16 h2 __attribute__((ext_vector_type(2)));

static __device__ __forceinline__ h2 f2h2(float a, float b){
    h2 r; r.x = (_Float16)a; r.y = (_Float16)b; return r;
}

#if defined(__has_builtin)
#if __has_builtin(__builtin_amdgcn_fdot2)
#define HAVE_FDOT2 1
#endif
#if __has_builtin(__builtin_amdgcn_sdot4)
#define HAVE_SDOT4 1
#endif
#endif

static __device__ __forceinline__ float fdot2(h2 a, h2 b, float c){
#ifdef HAVE_FDOT2
    return __builtin_amdgcn_fdot2(a, b, c, false);
#else
    asm("v_dot2_f32_f16 %0, %1, %2, %0" : "+v"(c) : "v"(a), "v"(b));
    return c;
#endif
}

static __device__ __forceinline__ int sdot4(int a, int b, int c){
#ifdef HAVE_SDOT4
    return __builtin_amdgcn_sdot4(a, b, c, false);
#else
    asm("v_dot4_i32_i8 %0, %1, %2, %0" : "+v"(c) : "v"(a), "v"(b));
    return c;
#endif
}

static __device__ __forceinline__ float fast_sig(float x){
    return 1.0f / (1.0f + __expf(-x));
}
static __device__ __forceinline__ float fast_tanh(float x){
    float ax = fabsf(x);
    float e = __expf(2.0f * ax);
    float t = 1.0f - 2.0f / (e + 1.0f);
    return copysignf(t, x);
}

// ---------------- kernel 0: quantize w_whh (1024x256 f32) to i8 + per-row scale
__global__ __launch_bounds__(64) void k_quant(const float* __restrict__ whh,
                                              int* __restrict__ wq,
                                              float* __restrict__ fsc){
    int r = blockIdx.x;          // 1024 rows
    int k = threadIdx.x;         // 64 lanes, 4 elems each
    float4 v = ((const float4*)(whh + (size_t)r * 256))[k];
    float m = fmaxf(fmaxf(fabsf(v.x), fabsf(v.y)), fmaxf(fabsf(v.z), fabsf(v.w)));
    #pragma unroll
    for (int off = 32; off; off >>= 1) m = fmaxf(m, __shfl_xor(m, off));
    float inv = (m > 0.f) ? (127.0f / m) : 0.0f;
    int q0 = ((int)rintf(v.x * inv)) & 255;
    int q1 = ((int)rintf(v.y * inv)) & 255;
    int q2 = ((int)rintf(v.z * inv)) & 255;
    int q3 = ((int)rintf(v.w * inv)) & 255;
    wq[r * 64 + k] = q0 | (q1 << 8) | (q2 << 16) | (q3 << 24);
    if (k == 0) fsc[r] = m * (1.0f / (127.0f * 127.0f));  // sw * sh, sh = 1/127
}

// ---------------- kernel 1: char LSTM (+ assemble wx = [word_emb | h_char])
__global__ __launch_bounds__(256) void k_char(const int* __restrict__ word_ixs,
                                              const int* __restrict__ char_ixs,
                                              const int* __restrict__ char_lens,
                                              const float* __restrict__ word_emb,
                                              const float* __restrict__ char_emb,
                                              const float* __restrict__ c_wih,
                                              const float* __restrict__ c_whh,
                                              const float* __restrict__ c_bih,
                                              const float* __restrict__ c_bhh,
                                              float* __restrict__ wx){
    __shared__ h2 xh[32];      // x_t as f16 pairs (64 vals)
    __shared__ h2 hh[32];      // h as f16 pairs (64 vals)
    __shared__ float zbuf[256];
    int tid = threadIdx.x;
    // per-thread weight row (row = tid of the 256 gate rows), f16-packed in regs
    h2 wi[32], wh[32];
    {
        const float2* a = (const float2*)(c_wih + (size_t)tid * 64);
        const float2* b = (const float2*)(c_whh + (size_t)tid * 64);
        #pragma unroll
        for (int d = 0; d < 32; ++d){ float2 v = a[d]; wi[d] = f2h2(v.x, v.y); }
        #pragma unroll
        for (int d = 0; d < 32; ++d){ float2 v = b[d]; wh[d] = f2h2(v.x, v.y); }
    }
    float cb = c_bih[tid] + c_bhh[tid];

    for (int w = 0; w < 4; ++w){
        int s = blockIdx.x * 4 + w;
        int len = char_lens[s];
        __syncthreads();                       // prev word's hh writes done
        if (tid < 32) hh[tid] = (h2)0.0f;
        float c_state = 0.f, h_state = 0.f;
        for (int t = 0; t < len; ++t){
            if (tid < 32){
                int ci = char_ixs[s * L_CH + t];
                float2 v = ((const float2*)(char_emb + (size_t)ci * 64))[tid];
                xh[tid] = f2h2(v.x, v.y);
            }
            __syncthreads();                   // x staged, h from prev step visible
            float acc = cb;
            #pragma unroll
            for (int d = 0; d < 32; ++d) acc = fdot2(wi[d], xh[d], acc);
            #pragma unroll
            for (int d = 0; d < 32; ++d) acc = fdot2(wh[d], hh[d], acc);
            zbuf[tid] = acc;
            __syncthreads();                   // z exchanged; hh reads done
            if (tid < 64){
                float zi = zbuf[tid], zf = zbuf[64 + tid];
                float zg = zbuf[128 + tid], zo = zbuf[192 + tid];
                c_state = fast_sig(zf) * c_state + fast_sig(zi) * fast_tanh(zg);
                h_state = fast_sig(zo) * fast_tanh(c_state);
                ((_Float16*)hh)[tid] = (_Float16)h_state;
            }
        }
        int wix = word_ixs[s];
        if (tid < 128) wx[(size_t)s * 192 + tid] = word_emb[(size_t)wix * 128 + tid];
        if (tid < 64)  wx[(size_t)s * 192 + 128 + tid] = h_state;
    }
}

// ---------------- kernel 2: zx = wx @ w_wih.T + (w_bih + w_bhh)
__global__ __launch_bounds__(128) void k_proj(const float* __restrict__ wx,
                                              const float* __restrict__ w_wih,
                                              const float* __restrict__ w_bih,
                                              const float* __restrict__ w_bhh,
                                              float* __restrict__ zx){
    __shared__ h2 xl[96];
    int tid = threadIdx.x;
    int jt = blockIdx.x & 7;        // 8 j-tiles of 128
    int sc = blockIdx.x >> 3;       // 128 s-chunks of 64
    int j  = jt * 128 + tid;
    h2 wreg[96];
    {
        const float2* wr = (const float2*)(w_wih + (size_t)j * 192);
        #pragma unroll
        for (int d = 0; d < 96; ++d){ float2 v = wr[d]; wreg[d] = f2h2(v.x, v.y); }
    }
    float wb = w_bih[j] + w_bhh[j];
    for (int i = 0; i < 64; ++i){
        int s = sc * 64 + i;
        __syncthreads();
        if (tid < 96){
            float2 v = ((const float2*)(wx + (size_t)s * 192))[tid];
            xl[tid] = f2h2(v.x, v.y);
        }
        __syncthreads();
        float acc = wb;
        #pragma unroll
        for (int d = 0; d < 96; ++d) acc = fdot2(wreg[d], xl[d], acc);
        zx[(size_t)s * 1024 + j] = acc;
    }
}

// ---------------- kernel 3: sequential word-LSTM scan (single workgroup)
// thread t owns gate rows r0=t, r1=t+512 of the 1024; i8 weights in VGPRs.
__global__ __launch_bounds__(512, 2) void k_scan(const float* __restrict__ zx,
                                                 const int* __restrict__ wq,
                                                 const float* __restrict__ fsc,
                                                 float* __restrict__ hs){
    __shared__ alignas(16) int hq[2][64];   // h quantized i8, double-buffered
    __shared__ float pbuf[256];             // i*tanh(g) exchange
    int tid = threadIdx.x;
    int r0 = tid, r1 = tid + 512;

    int w0[64], w1[64];
    {
        const int4* q0 = (const int4*)(wq + r0 * 64);
        const int4* q1 = (const int4*)(wq + r1 * 64);
        #pragma unroll
        for (int d = 0; d < 16; ++d){
            int4 v = q0[d];
            w0[4*d] = v.x; w0[4*d+1] = v.y; w0[4*d+2] = v.z; w0[4*d+3] = v.w;
        }
        #pragma unroll
        for (int d = 0; d < 16; ++d){
            int4 v = q1[d];
            w1[4*d] = v.x; w1[4*d+1] = v.y; w1[4*d+2] = v.z; w1[4*d+3] = v.w;
        }
    }
    float f0 = fsc[r0], f1 = fsc[r1];

    if (tid < 64) hq[0][tid] = 0;
    float c_state = 0.f;

    // zx prefetch, 2 steps ahead
    float za0 = zx[r0],        za1 = zx[r1];
    float zb0 = zx[1024 + r0], zb1 = zx[1024 + r1];
    __syncthreads();

    #pragma unroll 1
    for (int t = 0; t < S_LEN; ++t){
        float z0 = za0, z1 = za1;
        za0 = zb0; za1 = zb1;
        if (t + 2 < S_LEN){
            zb0 = zx[(size_t)(t + 2) * 1024 + r0];
            zb1 = zx[(size_t)(t + 2) * 1024 + r1];
        }
        int acc0 = 0, acc1 = 0;
        const int* hb = hq[t & 1];
        #pragma unroll
        for (int d4 = 0; d4 < 16; ++d4){
            int4 hv = ((const int4*)hb)[d4];
            acc0 = sdot4(w0[4*d4+0], hv.x, acc0); acc1 = sdot4(w1[4*d4+0], hv.x, acc1);
            acc0 = sdot4(w0[4*d4+1], hv.y, acc0); acc1 = sdot4(w1[4*d4+1], hv.y, acc1);
            acc0 = sdot4(w0[4*d4+2], hv.z, acc0); acc1 = sdot4(w1[4*d4+2], hv.z, acc1);
            acc0 = sdot4(w0[4*d4+3], hv.w, acc0); acc1 = sdot4(w1[4*d4+3], hv.w, acc1);
        }
        z0 += (float)acc0 * f0;   // + recurrent contribution
        z1 += (float)acc1 * f1;
        if (tid < 256){
            // r0 = i-row(tid), r1 = g-row(tid)
            pbuf[tid] = fast_sig(z0) * fast_tanh(z1);
        }
        __syncthreads();
        if (tid >= 256){
            // r0 = f-row(e), r1 = o-row(e)
            int e = tid - 256;
            float p = pbuf[e];
            c_state = fast_sig(z0) * c_state + p;
            float h = fast_sig(z1) * fast_tanh(c_state);
            hs[(size_t)t * 256 + e] = h;
            int q = (int)rintf(h * 127.0f);
            ((signed char*)hq[(t + 1) & 1])[e] = (signed char)q;
        }
        __syncthreads();
    }
}

// ---------------- kernel 4: logits + log_softmax
__global__ __launch_bounds__(128) void k_out(const float* __restrict__ hs,
                                             const float* __restrict__ out_w,
                                             const float* __restrict__ out_b,
                                             float* __restrict__ out){
    __shared__ float hl[256];
    __shared__ float red0[2];
    __shared__ float red1[2];
    int s = blockIdx.x, tid = threadIdx.x;
    hl[tid]       = hs[(size_t)s * 256 + tid];
    hl[tid + 128] = hs[(size_t)s * 256 + 128 + tid];
    __syncthreads();
    const float4* wr = (const float4*)(out_w + (size_t)tid * 256);
    float acc = out_b[tid];
    #pragma unroll 8
    for (int k = 0; k < 64; ++k){
        float4 v = wr[k];
        acc += v.x * hl[4*k] + v.y * hl[4*k+1] + v.z * hl[4*k+2] + v.w * hl[4*k+3];
    }
    float m = acc;
    #pragma unroll
    for (int off = 32; off; off >>= 1) m = fmaxf(m, __shfl_xor(m, off));
    if ((tid & 63) == 0) red0[tid >> 6] = m;
    __syncthreads();
    float M = fmaxf(red0[0], red0[1]);
    float e = __expf(acc - M);
    float ssum = e;
    #pragma unroll
    for (int off = 32; off; off >>= 1) ssum += __shfl_xor(ssum, off);
    if ((tid & 63) == 0) red1[tid >> 6] = ssum;
    __syncthreads();
    float Z = red1[0] + red1[1];
    out[(size_t)s * 128 + tid] = acc - M - __logf(Z);
}

extern "C" void kernel_launch(void* const* d_in, const int* in_sizes, int n_in,
                              void* d_out, int out_size, void* d_ws, size_t ws_size,
                              hipStream_t stream){
    const int*   word_ixs  = (const int*)  d_in[0];
    const int*   char_ixs  = (const int*)  d_in[1];
    const int*   char_lens = (const int*)  d_in[2];
    const float* word_emb  = (const float*)d_in[3];
    const float* char_emb  = (const float*)d_in[4];
    const float* c_wih     = (const float*)d_in[5];
    const float* c_whh     = (const float*)d_in[6];
    const float* c_bih     = (const float*)d_in[7];
    const float* c_bhh     = (const float*)d_in[8];
    const float* w_wih     = (const float*)d_in[9];
    const float* w_whh     = (const float*)d_in[10];
    const float* w_bih     = (const float*)d_in[11];
    const float* w_bhh     = (const float*)d_in[12];
    const float* out_w     = (const float*)d_in[13];
    const float* out_b     = (const float*)d_in[14];
    float* out = (float*)d_out;

    char* ws = (char*)d_ws;
    // workspace layout (all 16B aligned)
    const size_t OFF_WX  = 0;                        // 8192*192*4  = 6291456
    const size_t OFF_ZX  = OFF_WX + 6291456;         // 8192*1024*4 = 33554432
    const size_t OFF_HS  = OFF_ZX + 33554432;        // 8192*256*4  = 8388608
    const size_t OFF_WQ  = OFF_HS + 8388608;         // 1024*256    = 262144
    const size_t OFF_FS  = OFF_WQ + 262144;          // 1024*4      = 4096
    float* wx  = (float*)(ws + OFF_WX);
    float* zx  = (float*)(ws + OFF_ZX);
    float* hs  = (float*)(ws + OFF_HS);
    int*   wq  = (int*)  (ws + OFF_WQ);
    float* fsc = (float*)(ws + OFF_FS);

    k_quant<<<dim3(1024), dim3(64),  0, stream>>>(w_whh, wq, fsc);
    k_char <<<dim3(2048), dim3(256), 0, stream>>>(word_ixs, char_ixs, char_lens,
                                                  word_emb, char_emb,
                                                  c_wih, c_whh, c_bih, c_bhh, wx);
    k_proj <<<dim3(1024), dim3(128), 0, stream>>>(wx, w_wih, w_bih, w_bhh, zx);
    k_scan <<<dim3(1),    dim3(512), 0, stream>>>(zx, wq, fsc, hs);
    k_out  <<<dim3(8192), dim3(128), 0, stream>>>(hs, out_w, out_b, out);
}